// Round 5
// baseline (305.252 us; speedup 1.0000x reference)
//
#include <hip/hip_runtime.h>
#include <hip/hip_bf16.h>
#include <cstdint>

// GateAttention, restructured:
//   xcW|G1 = xc @ [WC | V_top]   (relu -> xcW bf16; G1 bf16)   [gemm4b, f32 A]
//   xqW|xqV = xq @ [WQ | V_bot]  (relu on xqW half)
//   attn: S = xcW.xqW^T, softmax+mask, O = P @ xqV, out = sigmoid(G1 + O)
// Round 5: gemm4b reads x_cont f32 directly (reg-staged A, deletes convert
// pass), 3-buffer depth-2 B prefetch, 1 barrier/K-tile, 32-MFMA clusters.
// attn: 64-row/4-wave blocks at 76.8KB LDS -> 2 blocks/CU.
// B=16, LC=2048, LQ=256, D=768, F=768.

using bf16 = __hip_bfloat16;
typedef __attribute__((ext_vector_type(8))) __bf16 bf16x8;
typedef __attribute__((ext_vector_type(4))) float f32x4;

typedef __attribute__((address_space(1))) const uint32_t GU32;
typedef __attribute__((address_space(3))) uint32_t LU32;

__device__ __forceinline__ void gll16(const bf16* g, bf16* l) {
  __builtin_amdgcn_global_load_lds((GU32*)g, (LU32*)l, 16, 0, 0);
}
__device__ __forceinline__ f32x4 mfma_bf16(bf16x8 a, bf16x8 b, f32x4 c) {
  return __builtin_amdgcn_mfma_f32_16x16x32_bf16(a, b, c, 0, 0, 0);
}
__device__ __forceinline__ bf16x8 ld_frag(const bf16* p) {
  return *reinterpret_cast<const bf16x8*>(p);
}
// LDS chunk swizzle (4 chunks of 16B per 64B row)
__device__ __forceinline__ int swz(int r) { return (r & 3) ^ ((r >> 2) & 1); }

__device__ __forceinline__ unsigned short f2bf_bits(float x) {
  bf16 b = __float2bfloat16(x);
  union { bf16 b; unsigned short s; } u;
  u.b = b;
  return u.s;
}
__device__ __forceinline__ bf16x8 pack_bf16x8(f32x4 a, f32x4 b) {
  union { bf16x8 v; bf16 e[8]; } u;
#pragma unroll
  for (int i = 0; i < 4; ++i) u.e[i] = __float2bfloat16(a[i]);
#pragma unroll
  for (int i = 0; i < 4; ++i) u.e[4 + i] = __float2bfloat16(b[i]);
  return u.v;
}

// ---------- 4x fused transpose f32 [768][768] -> bf16 [768][768]^T ----------
__global__ void transpose4(const float* __restrict__ s0, const float* __restrict__ s1,
                           const float* __restrict__ s2, const float* __restrict__ s3,
                           bf16* __restrict__ d0, bf16* __restrict__ d1,
                           bf16* __restrict__ d2, bf16* __restrict__ d3) {
  __shared__ float tile[32][33];
  const int z = blockIdx.z;
  const float* in = (z == 0) ? s0 : (z == 1) ? s1 : (z == 2) ? s2 : s3;
  bf16* out = (z == 0) ? d0 : (z == 1) ? d1 : (z == 2) ? d2 : d3;
  int c0 = blockIdx.x * 32, r0 = blockIdx.y * 32;
  int tx = threadIdx.x, ty = threadIdx.y;
#pragma unroll
  for (int i = ty; i < 32; i += 8)
    tile[i][tx] = in[(long)(r0 + i) * 768 + (c0 + tx)];
  __syncthreads();
#pragma unroll
  for (int i = ty; i < 32; i += 8)
    out[(long)(c0 + i) * 768 + (r0 + tx)] = __float2bfloat16(tile[tx][i]);
}

// ---------- transpose bf16 [R][C] -> bf16 [C][R], batched ----------
__global__ void transpose_bf16(const bf16* __restrict__ in, bf16* __restrict__ out,
                               int R, int C, long ibs, long obs) {
  __shared__ bf16 tile[32][33];
  const bf16* inb = in + (long)blockIdx.z * ibs;
  bf16* outb = out + (long)blockIdx.z * obs;
  int c0 = blockIdx.x * 32, r0 = blockIdx.y * 32;
  int tx = threadIdx.x, ty = threadIdx.y;
#pragma unroll
  for (int i = ty; i < 32; i += 8)
    tile[i][tx] = inb[(long)(r0 + i) * C + (c0 + tx)];
  __syncthreads();
#pragma unroll
  for (int i = ty; i < 32; i += 8)
    outb[(long)(c0 + i) * R + (r0 + tx)] = tile[tx][i];
}

// ---------- flat f32 -> bf16 convert ----------
__global__ void convert_flat(const float* __restrict__ in, bf16* __restrict__ out, long n4) {
  long i = (long)blockIdx.x * blockDim.x + threadIdx.x;
  if (i >= n4) return;
  float4 v = reinterpret_cast<const float4*>(in)[i];
  ushort4 o;
  o.x = f2bf_bits(v.x);
  o.y = f2bf_bits(v.y);
  o.z = f2bf_bits(v.z);
  o.w = f2bf_bits(v.w);
  reinterpret_cast<ushort4*>(out)[i] = o;
}

// ---------- 128x128 GEMM with split epilogue (small xq projection) ----------
__global__ __launch_bounds__(256) void gemm_bt_split(
    const bf16* __restrict__ A, long lda,
    const bf16* __restrict__ Bt, long ldb,
    bf16* __restrict__ O1, bf16* __restrict__ O2, int K) {
  __shared__ __align__(16) bf16 As[128 * 32];
  __shared__ __align__(16) bf16 Bs[128 * 32];
  const int tid = threadIdx.x;
  const int wave = tid >> 6;
  const int lane = tid & 63;
  const int l16 = lane & 15;
  const int kh = lane >> 4;
  const int wm = (wave >> 1) * 64;
  const int wn = (wave & 1) * 64;
  const long row0 = (long)blockIdx.x * 128;
  const long col0 = (long)blockIdx.y * 128;
  const int srow = tid >> 2;
  const int scol = ((tid & 3) ^ swz(srow)) * 8;

  const bf16* ap0 = A + (row0 + srow) * lda + scol;
  const bf16* ap1 = ap0 + 64 * lda;
  const bf16* bp0 = Bt + (col0 + srow) * ldb + scol;
  const bf16* bp1 = bp0 + 64 * ldb;
  bf16* as0 = As + wave * 512;
  bf16* as1 = as0 + 2048;
  bf16* bs0 = Bs + wave * 512;
  bf16* bs1 = bs0 + 2048;

  const int xc = (kh ^ swz(l16)) * 8;
  f32x4 acc[4][4] = {};

  for (int k0 = 0; k0 < K; k0 += 32) {
    gll16(ap0 + k0, as0);
    gll16(ap1 + k0, as1);
    gll16(bp0 + k0, bs0);
    gll16(bp1 + k0, bs1);
    __syncthreads();
    bf16x8 af[4], bfr[4];
#pragma unroll
    for (int i = 0; i < 4; ++i)
      af[i] = ld_frag(As + (wm + i * 16 + l16) * 32 + xc);
#pragma unroll
    for (int j = 0; j < 4; ++j)
      bfr[j] = ld_frag(Bs + (wn + j * 16 + l16) * 32 + xc);
#pragma unroll
    for (int i = 0; i < 4; ++i)
#pragma unroll
      for (int j = 0; j < 4; ++j)
        acc[i][j] = mfma_bf16(af[i], bfr[j], acc[i][j]);
    __syncthreads();
  }

  const bool isO1 = col0 < 768;
#pragma unroll
  for (int i = 0; i < 4; ++i)
#pragma unroll
    for (int j = 0; j < 4; ++j)
#pragma unroll
      for (int r = 0; r < 4; ++r) {
        long row = row0 + wm + i * 16 + kh * 4 + r;
        long col = col0 + wn + j * 16 + l16;
        float v = acc[i][j][r];
        if (isO1)
          O1[row * 768 + col] = __float2bfloat16(fmaxf(v, 0.0f));
        else
          O2[row * 768 + (col - 768)] = __float2bfloat16(v);
      }
}

// ---------- 256x256 GEMM, f32 A reg-staged, BK=32, 3 bufs, 1 barrier/tile ---
// A = x_cont f32 [32768][768]; Bt = [Wct] bf16 [1536][768], K=768.
// cols [0,768): relu -> O1 bf16 (xcW) ; cols [768,1536): plain -> O2 bf16 (G1)
// Ledger/wave: top of t issues 4 A-f32(t+1) + 2 B-gll16(t+2);
// end of t: vmcnt(2) completes B(t+1)+A(t+1), write A(t+1), lgkm0+barrier.
__global__ __launch_bounds__(512) void gemm4b(
    const float* __restrict__ Af, const bf16* __restrict__ Bt,
    bf16* __restrict__ O1, bf16* __restrict__ O2) {
  extern __shared__ __align__(16) bf16 smem[];  // 3 bufs x (A 8192 + B 8192) els
  const int tid = threadIdx.x;
  const int wid = tid >> 6;
  const int lane = tid & 63;
  const int l15 = lane & 15;
  const int g = lane >> 4;
  const int wm = wid >> 2;
  const int wn = wid & 3;

  // panel-major + XCD-chunked: XCD x runs wgids x*96..x*96+95 (6 per A-panel)
  const int lin = blockIdx.x;          // 0..767
  const int xcd = lin & 7;
  const int jj = lin >> 3;             // 0..95
  const int wgid = xcd * 96 + jj;
  const long row0 = (long)(wgid / 6) * 256;
  const long col0 = (long)(wgid % 6) * 256;

  // A reg-stage mapping: thread -> (row, k-half)
  const int arow = tid >> 1;           // 0..255
  const int ahalf = tid & 1;           // 16 f32 each
  const float* Ap = Af + (row0 + arow) * 768 + ahalf * 16;
  const int awz = swz(arow & 15);

  // B gll16 mapping (pre-swizzled source)
  const int srow = lane >> 2;
  const int sc = ((lane & 3) ^ swz(srow)) * 8;
  const int w16 = wid * 16;
  const bf16* Bb = Bt + (col0 + srow) * 768 + sc;

  f32x4 acc[8][4] = {};

  auto stageB = [&](int buf, int kk) {
    bf16* d = smem + buf * 16384 + 8192 + w16 * 32;
    gll16(Bb + (long)w16 * 768 + kk, d);
    gll16(Bb + (long)(128 + w16) * 768 + kk, d + 128 * 32);
  };
  auto writeA = [&](int buf, const f32x4* ar) {
    bf16* base = smem + buf * 16384 + arow * 32;
#pragma unroll
    for (int q = 0; q < 2; ++q) {
      int c = ahalf * 2 + q;
      *reinterpret_cast<bf16x8*>(base + ((c ^ awz) * 8)) =
          pack_bf16x8(ar[2 * q], ar[2 * q + 1]);
    }
  };
  const int xc = (g ^ swz(l15)) * 8;
  auto ldA = [&](int buf, int m) {
    int row = wm * 128 + m * 16 + l15;
    return ld_frag(smem + buf * 16384 + row * 32 + xc);
  };
  auto ldB = [&](int buf, int n) {
    int row = wn * 64 + n * 16 + l15;
    return ld_frag(smem + buf * 16384 + 8192 + row * 32 + xc);
  };

  // prologue: A(0) regs, B(0), B(1) gll16
  f32x4 ar[4];
#pragma unroll
  for (int q = 0; q < 4; ++q) ar[q] = *reinterpret_cast<const f32x4*>(Ap + q * 4);
  stageB(0, 0);
  stageB(1, 32);
  asm volatile("s_waitcnt vmcnt(4)" ::: "memory");   // A(0) done
  writeA(0, ar);
  asm volatile("s_waitcnt vmcnt(2) lgkmcnt(0)\n\ts_barrier" ::: "memory");  // B(0) done

  for (int t = 0; t < 24; ++t) {
    const int cur = t % 3;
    const int nxtb = (t + 1) % 3;
    const int pf2b = (t + 2) % 3;

    bf16x8 av[8], bv[4];
#pragma unroll
    for (int n = 0; n < 4; ++n) bv[n] = ldB(cur, n);
#pragma unroll
    for (int m = 0; m < 8; ++m) av[m] = ldA(cur, m);
    if (t + 1 < 24) {
      const float* ap = Ap + (t + 1) * 32;
#pragma unroll
      for (int q = 0; q < 4; ++q) ar[q] = *reinterpret_cast<const f32x4*>(ap + q * 4);
    }
    if (t + 2 < 24) stageB(pf2b, (t + 2) * 32);
    __builtin_amdgcn_sched_barrier(0);

    __builtin_amdgcn_s_setprio(1);
#pragma unroll
    for (int m = 0; m < 8; ++m)
#pragma unroll
      for (int n = 0; n < 4; ++n)
        acc[m][n] = mfma_bf16(av[m], bv[n], acc[m][n]);
    __builtin_amdgcn_s_setprio(0);

    if (t + 1 < 24) {
      if (t + 2 < 24)
        asm volatile("s_waitcnt vmcnt(2)" ::: "memory");   // B(t+1)+A(t+1) done
      else
        asm volatile("s_waitcnt vmcnt(0)" ::: "memory");
      writeA(nxtb, ar);
      asm volatile("s_waitcnt lgkmcnt(0)\n\ts_barrier" ::: "memory");
    }
  }

  const bool isO1 = col0 < 768;
#pragma unroll
  for (int m = 0; m < 8; ++m)
#pragma unroll
    for (int n = 0; n < 4; ++n)
#pragma unroll
      for (int r = 0; r < 4; ++r) {
        long row = row0 + wm * 128 + m * 16 + g * 4 + r;
        long col = col0 + wn * 64 + n * 16 + l15;
        float v = acc[m][n][r];
        if (isO1)
          O1[row * 768 + col] = __float2bfloat16(fmaxf(v, 0.0f));
        else
          O2[row * 768 + (col - 768)] = __float2bfloat16(v);
      }
}

// ---------- fused attention + gate: 64 c-rows, 4 waves, 2 blocks/CU --------
// LDS (bf16 el): As[2][2048] @0, Bs[2][8192] @4096, P[64*264] @20480,
// wred f32[256] @ el 37376, wsum @ +512 el. Total 76800 B.
__global__ __launch_bounds__(256) void attn_kernel(
    const bf16* __restrict__ xcW, const bf16* __restrict__ xqW,
    const bf16* __restrict__ xqVT, const bf16* __restrict__ G1,
    const int* __restrict__ qlen_arr, float* __restrict__ out) {
  extern __shared__ __align__(16) bf16 smem[];
  bf16* P = smem + 20480;
  float* wred = (float*)(smem + 37376);   // [64][4]
  float* wsum = wred + 256;               // [64][4]

  // XCD-chunked: XCD x serves batches 2x,2x+1 (32 c-tiles each)
  const int n = blockIdx.x;       // 0..511
  const int xcd = n & 7;
  const int idx = n >> 3;         // 0..63
  const int b = xcd * 2 + (idx >> 5);
  const int ct = idx & 31;

  const int tid = threadIdx.x;
  const int wc = tid >> 6;        // 0..3
  const int lane = tid & 63;
  const int l16 = lane & 15;
  const int kh = lane >> 4;

  const long crow0 = (long)b * 2048 + (long)ct * 64;
  const int srow = lane >> 2;
  const int sc = ((lane & 3) ^ swz(srow)) * 8;
  const int xcr = (kh ^ swz(l16)) * 8;

  const bf16* ap = xcW + (crow0 + wc * 16 + srow) * 768 + sc;
  const bf16* bp = xqW + ((long)b * 256 + wc * 64 + srow) * 768 + sc;

  auto stage = [&](int bufi, int k0) {
    gll16(ap + k0, smem + bufi * 2048 + wc * 512);
    bf16* bd = smem + 4096 + bufi * 8192 + wc * 2048;
#pragma unroll
    for (int q = 0; q < 4; ++q)
      gll16(bp + q * 16 * 768 + k0, bd + q * 512);
  };

  f32x4 acc[4][4] = {};
  stage(0, 0);

  for (int t = 0; t < 24; ++t) {
    const int cur = t & 1;
    if (t + 1 < 24) {
      stage(cur ^ 1, (t + 1) * 32);
      asm volatile("s_waitcnt vmcnt(5)\n\ts_barrier" ::: "memory");
    } else {
      asm volatile("s_waitcnt vmcnt(0)\n\ts_barrier" ::: "memory");
    }
    const bf16* Ac = smem + cur * 2048;
    const bf16* Bc = smem + 4096 + cur * 8192;
    bf16x8 af[4], bfr[4];
#pragma unroll
    for (int i = 0; i < 4; ++i)
      af[i] = ld_frag(Ac + (i * 16 + l16) * 32 + xcr);
#pragma unroll
    for (int j = 0; j < 4; ++j)
      bfr[j] = ld_frag(Bc + (wc * 64 + j * 16 + l16) * 32 + xcr);
    __builtin_amdgcn_s_setprio(1);
#pragma unroll
    for (int i = 0; i < 4; ++i)
#pragma unroll
      for (int j = 0; j < 4; ++j)
        acc[i][j] = mfma_bf16(af[i], bfr[j], acc[i][j]);
    __builtin_amdgcn_s_setprio(0);
    __builtin_amdgcn_s_barrier();
  }

  const float scale = 0.036084391824351615f;  // 1/sqrt(768)
  const int qlen = qlen_arr[b];

#pragma unroll
  for (int i = 0; i < 4; ++i)
#pragma unroll
    for (int j = 0; j < 4; ++j) {
      int col = wc * 64 + j * 16 + l16;
      float m = (col >= qlen) ? -1.0e12f : 0.0f;
#pragma unroll
      for (int r = 0; r < 4; ++r)
        acc[i][j][r] = acc[i][j][r] * scale + m;
    }

#pragma unroll
  for (int i = 0; i < 4; ++i)
#pragma unroll
    for (int r = 0; r < 4; ++r) {
      float mx = fmaxf(fmaxf(acc[i][0][r], acc[i][1][r]),
                       fmaxf(acc[i][2][r], acc[i][3][r]));
      mx = fmaxf(mx, __shfl_xor(mx, 1));
      mx = fmaxf(mx, __shfl_xor(mx, 2));
      mx = fmaxf(mx, __shfl_xor(mx, 4));
      mx = fmaxf(mx, __shfl_xor(mx, 8));
      if (l16 == 0) wred[(i * 16 + kh * 4 + r) * 4 + wc] = mx;
    }
  __syncthreads();

#pragma unroll
  for (int i = 0; i < 4; ++i)
#pragma unroll
    for (int r = 0; r < 4; ++r) {
      int row = i * 16 + kh * 4 + r;
      float gm = fmaxf(fmaxf(wred[row * 4 + 0], wred[row * 4 + 1]),
                       fmaxf(wred[row * 4 + 2], wred[row * 4 + 3]));
      float s = 0.0f;
#pragma unroll
      for (int j = 0; j < 4; ++j) {
        float e = expf(acc[i][j][r] - gm);
        acc[i][j][r] = e;
        s += e;
      }
      s += __shfl_xor(s, 1);
      s += __shfl_xor(s, 2);
      s += __shfl_xor(s, 4);
      s += __shfl_xor(s, 8);
      if (l16 == 0) wsum[row * 4 + wc] = s;
    }
  __syncthreads();

#pragma unroll
  for (int i = 0; i < 4; ++i)
#pragma unroll
    for (int r = 0; r < 4; ++r) {
      int row = i * 16 + kh * 4 + r;
      float inv = 1.0f / (wsum[row * 4 + 0] + wsum[row * 4 + 1] +
                          wsum[row * 4 + 2] + wsum[row * 4 + 3]);
#pragma unroll
      for (int j = 0; j < 4; ++j)
        P[row * 264 + wc * 64 + j * 16 + l16] = __float2bfloat16(acc[i][j][r] * inv);
    }
  __syncthreads();

  // hoist P fragments (reused across all 3 nb sweeps)
  bf16x8 pf[4][8];
#pragma unroll
  for (int i = 0; i < 4; ++i)
#pragma unroll
    for (int kk = 0; kk < 8; ++kk)
      pf[i][kk] = ld_frag(P + (i * 16 + l16) * 264 + kk * 32 + kh * 8);

  for (int nb = 0; nb < 3; ++nb) {
    const int n0 = nb * 256 + wc * 64;
    const bf16* btp = xqVT + ((long)b * 768 + n0) * 256;
    f32x4 a2[4][4] = {};
#pragma unroll
    for (int kk = 0; kk < 8; ++kk) {
      bf16x8 vf[4];
#pragma unroll
      for (int j = 0; j < 4; ++j)
        vf[j] = ld_frag(btp + (j * 16 + l16) * 256 + kk * 32 + kh * 8);
#pragma unroll
      for (int i = 0; i < 4; ++i)
#pragma unroll
        for (int j = 0; j < 4; ++j)
          a2[i][j] = mfma_bf16(pf[i][kk], vf[j], a2[i][j]);
    }
#pragma unroll
    for (int i = 0; i < 4; ++i)
#pragma unroll
      for (int j = 0; j < 4; ++j)
#pragma unroll
        for (int r = 0; r < 4; ++r) {
          long row = crow0 + i * 16 + kh * 4 + r;
          int col = n0 + j * 16 + l16;
          float v = a2[i][j][r] + __bfloat162float(G1[row * 768 + col]);
          out[row * 768 + col] = 1.0f / (1.0f + __expf(-v));
        }
  }
}

extern "C" void kernel_launch(void* const* d_in, const int* in_sizes, int n_in,
                              void* d_out, int out_size, void* d_ws, size_t ws_size,
                              hipStream_t stream) {
  const float* x_cont = (const float*)d_in[0];  // [16,2048,768]
  const float* x_ques = (const float*)d_in[1];  // [16,256,768]
  const int* ques_len = (const int*)d_in[2];    // [16]
  const float* WC = (const float*)d_in[3];      // [768,768]
  const float* WQ = (const float*)d_in[4];      // [768,768]
  const float* V = (const float*)d_in[5];       // [1536,768]
  float* out = (float*)d_out;                   // [32768,768] f32

  // ws layout (bf16 elements)
  bf16* Wct = (bf16*)d_ws;                       // [1536][768] = [WC^T ; Vtop^T]
  bf16* Wqt = Wct + (long)1536 * 768;            // [1536][768] = [WQ^T ; Vbot^T]
  bf16* xqB = Wqt + (long)1536 * 768;            // [4096][768]
  bf16* xcW = xqB + (long)4096 * 768;            // [32768][768]
  bf16* xqW = xcW + (long)32768 * 768;           // [4096][768]
  bf16* xqV = xqW + (long)4096 * 768;            // [4096][768]
  bf16* xqVT = xqV + (long)4096 * 768;           // [16][768][256]
  bf16* G1 = xqVT + (long)16 * 768 * 256;        // [32768][768]

  (void)hipFuncSetAttribute(reinterpret_cast<const void*>(&gemm4b),
                            hipFuncAttributeMaxDynamicSharedMemorySize, 98304);
  (void)hipFuncSetAttribute(reinterpret_cast<const void*>(&attn_kernel),
                            hipFuncAttributeMaxDynamicSharedMemorySize, 76800);

  // weight prep: Wct = [WC^T ; Vtop^T], Wqt = [WQ^T ; Vbot^T]
  transpose4<<<dim3(24, 24, 4), dim3(32, 8), 0, stream>>>(
      WC, WQ, V, V + (long)768 * 768,
      Wct, Wqt, Wct + (long)768 * 768, Wqt + (long)768 * 768);

  // xq convert + fused projection + transpose
  convert_flat<<<3072, 256, 0, stream>>>(x_ques, xqB, (long)4096 * 768 / 4);
  gemm_bt_split<<<dim3(32, 12), 256, 0, stream>>>(xqB, 768, Wqt, 768, xqW, xqV, 768);
  transpose_bf16<<<dim3(24, 8, 16), dim3(32, 8), 0, stream>>>(
      xqV, xqVT, 256, 768, (long)256 * 768, (long)768 * 256);

  // xc fused projection straight from f32 input
  gemm4b<<<768, 512, 98304, stream>>>(x_cont, Wct, xcW, G1);

  // attention + gate epilogue
  attn_kernel<<<512, 256, 76800, stream>>>(xcW, xqW, xqVT, G1, ques_len, out);
}

// Round 6
// 264.923 us; speedup vs baseline: 1.1522x; 1.1522x over previous
//
#include <hip/hip_runtime.h>
#include <hip/hip_bf16.h>
#include <cstdint>

// GateAttention, restructured:
//   xcW|G1 = xc @ [WC | V_top]   (relu on xcW half; G1 bf16 -> ws)
//   xqW|xqV = xq @ [WQ | V_bot]  (relu on xqW half)
//   attn: S = xcW.xqW^T, softmax+mask, O = P @ xqV, out = sigmoid(G1 + O)
// Round 6: gemm4b reverted to round-4 (107us proven). attn: exact qlen-skip
// (masked cols give exp->0 exactly), 512 x 64-row blocks for dynamic balance,
// per-wave vmcnt ledger (active 5 / inactive 1).
// B=16, LC=2048, LQ=256, D=768, F=768.

using bf16 = __hip_bfloat16;
typedef __attribute__((ext_vector_type(8))) __bf16 bf16x8;
typedef __attribute__((ext_vector_type(4))) float f32x4;

typedef __attribute__((address_space(1))) const uint32_t GU32;
typedef __attribute__((address_space(3))) uint32_t LU32;

__device__ __forceinline__ void gll16(const bf16* g, bf16* l) {
  __builtin_amdgcn_global_load_lds((GU32*)g, (LU32*)l, 16, 0, 0);
}
__device__ __forceinline__ f32x4 mfma_bf16(bf16x8 a, bf16x8 b, f32x4 c) {
  return __builtin_amdgcn_mfma_f32_16x16x32_bf16(a, b, c, 0, 0, 0);
}
__device__ __forceinline__ bf16x8 ld_frag(const bf16* p) {
  return *reinterpret_cast<const bf16x8*>(p);
}
// LDS chunk swizzle (4 chunks of 16B per 64B row)
__device__ __forceinline__ int swz(int r) { return (r & 3) ^ ((r >> 2) & 1); }

__device__ __forceinline__ unsigned short f2bf_bits(float x) {
  bf16 b = __float2bfloat16(x);
  union { bf16 b; unsigned short s; } u;
  u.b = b;
  return u.s;
}

// ---------- 4x fused transpose f32 [768][768] -> bf16 [768][768]^T ----------
__global__ void transpose4(const float* __restrict__ s0, const float* __restrict__ s1,
                           const float* __restrict__ s2, const float* __restrict__ s3,
                           bf16* __restrict__ d0, bf16* __restrict__ d1,
                           bf16* __restrict__ d2, bf16* __restrict__ d3) {
  __shared__ float tile[32][33];
  const int z = blockIdx.z;
  const float* in = (z == 0) ? s0 : (z == 1) ? s1 : (z == 2) ? s2 : s3;
  bf16* out = (z == 0) ? d0 : (z == 1) ? d1 : (z == 2) ? d2 : d3;
  int c0 = blockIdx.x * 32, r0 = blockIdx.y * 32;
  int tx = threadIdx.x, ty = threadIdx.y;
#pragma unroll
  for (int i = ty; i < 32; i += 8)
    tile[i][tx] = in[(long)(r0 + i) * 768 + (c0 + tx)];
  __syncthreads();
#pragma unroll
  for (int i = ty; i < 32; i += 8)
    out[(long)(c0 + i) * 768 + (r0 + tx)] = __float2bfloat16(tile[tx][i]);
}

// ---------- transpose bf16 [R][C] -> bf16 [C][R], batched ----------
__global__ void transpose_bf16(const bf16* __restrict__ in, bf16* __restrict__ out,
                               int R, int C, long ibs, long obs) {
  __shared__ bf16 tile[32][33];
  const bf16* inb = in + (long)blockIdx.z * ibs;
  bf16* outb = out + (long)blockIdx.z * obs;
  int c0 = blockIdx.x * 32, r0 = blockIdx.y * 32;
  int tx = threadIdx.x, ty = threadIdx.y;
#pragma unroll
  for (int i = ty; i < 32; i += 8)
    tile[i][tx] = inb[(long)(r0 + i) * C + (c0 + tx)];
  __syncthreads();
#pragma unroll
  for (int i = ty; i < 32; i += 8)
    outb[(long)(c0 + i) * R + (r0 + tx)] = tile[tx][i];
}

// ---------- flat f32 -> bf16 convert ----------
__global__ void convert_flat(const float* __restrict__ in, bf16* __restrict__ out, long n4) {
  long i = (long)blockIdx.x * blockDim.x + threadIdx.x;
  if (i >= n4) return;
  float4 v = reinterpret_cast<const float4*>(in)[i];
  ushort4 o;
  o.x = f2bf_bits(v.x);
  o.y = f2bf_bits(v.y);
  o.z = f2bf_bits(v.z);
  o.w = f2bf_bits(v.w);
  reinterpret_cast<ushort4*>(out)[i] = o;
}

// ---------- 128x128 GEMM with split epilogue (small xq projection) ----------
__global__ __launch_bounds__(256) void gemm_bt_split(
    const bf16* __restrict__ A, long lda,
    const bf16* __restrict__ Bt, long ldb,
    bf16* __restrict__ O1, bf16* __restrict__ O2, int K) {
  __shared__ __align__(16) bf16 As[128 * 32];
  __shared__ __align__(16) bf16 Bs[128 * 32];
  const int tid = threadIdx.x;
  const int wave = tid >> 6;
  const int lane = tid & 63;
  const int l16 = lane & 15;
  const int kh = lane >> 4;
  const int wm = (wave >> 1) * 64;
  const int wn = (wave & 1) * 64;
  const long row0 = (long)blockIdx.x * 128;
  const long col0 = (long)blockIdx.y * 128;
  const int srow = tid >> 2;
  const int scol = ((tid & 3) ^ swz(srow)) * 8;

  const bf16* ap0 = A + (row0 + srow) * lda + scol;
  const bf16* ap1 = ap0 + 64 * lda;
  const bf16* bp0 = Bt + (col0 + srow) * ldb + scol;
  const bf16* bp1 = bp0 + 64 * ldb;
  bf16* as0 = As + wave * 512;
  bf16* as1 = as0 + 2048;
  bf16* bs0 = Bs + wave * 512;
  bf16* bs1 = bs0 + 2048;

  const int xc = (kh ^ swz(l16)) * 8;
  f32x4 acc[4][4] = {};

  for (int k0 = 0; k0 < K; k0 += 32) {
    gll16(ap0 + k0, as0);
    gll16(ap1 + k0, as1);
    gll16(bp0 + k0, bs0);
    gll16(bp1 + k0, bs1);
    __syncthreads();
    bf16x8 af[4], bfr[4];
#pragma unroll
    for (int i = 0; i < 4; ++i)
      af[i] = ld_frag(As + (wm + i * 16 + l16) * 32 + xc);
#pragma unroll
    for (int j = 0; j < 4; ++j)
      bfr[j] = ld_frag(Bs + (wn + j * 16 + l16) * 32 + xc);
#pragma unroll
    for (int i = 0; i < 4; ++i)
#pragma unroll
      for (int j = 0; j < 4; ++j)
        acc[i][j] = mfma_bf16(af[i], bfr[j], acc[i][j]);
    __syncthreads();
  }

  const bool isO1 = col0 < 768;
#pragma unroll
  for (int i = 0; i < 4; ++i)
#pragma unroll
    for (int j = 0; j < 4; ++j)
#pragma unroll
      for (int r = 0; r < 4; ++r) {
        long row = row0 + wm + i * 16 + kh * 4 + r;
        long col = col0 + wn + j * 16 + l16;
        float v = acc[i][j][r];
        if (isO1)
          O1[row * 768 + col] = __float2bfloat16(fmaxf(v, 0.0f));
        else
          O2[row * 768 + (col - 768)] = __float2bfloat16(v);
      }
}

// ---------- 256x256 GEMM, BK=32, 4-buffer LDS, 3-tile prefetch depth -------
// cols [0,768): relu -> O1 bf16 (xcW) ; cols [768,1536): plain -> O2 bf16 (G1).
__global__ __launch_bounds__(512, 2) void gemm4b(
    const bf16* __restrict__ A, long lda,
    const bf16* __restrict__ Bt, long ldb,
    bf16* __restrict__ O1, bf16* __restrict__ O2, int K) {
  extern __shared__ __align__(16) bf16 smem[];  // 4 bufs x (A 8192 + B 8192) bf16
  const int tid = threadIdx.x;
  const int wid = tid >> 6;
  const int lane = tid & 63;
  const int l15 = lane & 15;
  const int g = lane >> 4;
  const int wm = wid >> 2;
  const int wn = wid & 3;

  const int lin = blockIdx.x;          // 0..767
  const int per = (int)gridDim.x >> 3; // 96
  const int wgid = (lin & 7) * per + (lin >> 3);
  const long row0 = (long)(wgid / 6) * 256;
  const long col0 = (long)(wgid % 6) * 256;

  const int srow = lane >> 2;
  const int sc = ((lane & 3) ^ swz(srow)) * 8;
  const int w16 = wid * 16;
  const bf16* Ab = A + (row0 + srow) * lda + sc;
  const bf16* Bb = Bt + (col0 + srow) * ldb + sc;

  f32x4 acc[8][4] = {};

  auto stageA = [&](int buf, int kk) {
    bf16* d = smem + buf * 16384 + w16 * 32;
    gll16(Ab + (long)w16 * lda + kk, d);
    gll16(Ab + (long)(128 + w16) * lda + kk, d + 128 * 32);
  };
  auto stageB = [&](int buf, int kk) {
    bf16* d = smem + buf * 16384 + 8192 + w16 * 32;
    gll16(Bb + (long)w16 * ldb + kk, d);
    gll16(Bb + (long)(128 + w16) * ldb + kk, d + 128 * 32);
  };
  const int xc = (g ^ swz(l15)) * 8;
  auto ldA = [&](int buf, int m) {
    int row = wm * 128 + m * 16 + l15;
    return ld_frag(smem + buf * 16384 + row * 32 + xc);
  };
  auto ldB = [&](int buf, int n) {
    int row = wn * 64 + n * 16 + l15;
    return ld_frag(smem + buf * 16384 + 8192 + row * 32 + xc);
  };

  stageA(0, 0);
  stageB(0, 0);
  stageA(1, 32);
  stageB(1, 32);
  stageA(2, 64);
  stageB(2, 64);
  asm volatile("s_waitcnt vmcnt(8)\n\ts_barrier" ::: "memory");

  const int NT = K >> 5;  // 24
  bf16x8 av[4], bv[4];

  for (int t = 0; t < NT; ++t) {
    const int cur = t & 3;
    const int pfb = (t + 3) & 3;
    const bool pf = (t + 3) < NT;
    const int kk = (t + 3) << 5;

#pragma unroll
    for (int n = 0; n < 4; ++n) bv[n] = ldB(cur, n);
#pragma unroll
    for (int m = 0; m < 4; ++m) av[m] = ldA(cur, m);
    if (pf) stageA(pfb, kk);
    __builtin_amdgcn_s_barrier();
    __builtin_amdgcn_s_setprio(1);
#pragma unroll
    for (int m = 0; m < 4; ++m)
#pragma unroll
      for (int n = 0; n < 4; ++n) acc[m][n] = mfma_bf16(av[m], bv[n], acc[m][n]);
    __builtin_amdgcn_s_setprio(0);
    __builtin_amdgcn_s_barrier();

#pragma unroll
    for (int m = 0; m < 4; ++m) av[m] = ldA(cur, 4 + m);
    if (pf) stageB(pfb, kk);
    __builtin_amdgcn_s_barrier();
    __builtin_amdgcn_s_setprio(1);
#pragma unroll
    for (int m = 0; m < 4; ++m)
#pragma unroll
      for (int n = 0; n < 4; ++n)
        acc[4 + m][n] = mfma_bf16(av[m], bv[n], acc[4 + m][n]);
    __builtin_amdgcn_s_setprio(0);

    if (t <= NT - 4)
      asm volatile("s_waitcnt vmcnt(8)\n\ts_barrier" ::: "memory");
    else if (t == NT - 3)
      asm volatile("s_waitcnt vmcnt(4)\n\ts_barrier" ::: "memory");
    else if (t == NT - 2)
      asm volatile("s_waitcnt vmcnt(0)\n\ts_barrier" ::: "memory");
  }

  const bool isO1 = col0 < 768;
#pragma unroll
  for (int m = 0; m < 8; ++m)
#pragma unroll
    for (int n = 0; n < 4; ++n)
#pragma unroll
      for (int r = 0; r < 4; ++r) {
        long row = row0 + wm * 128 + m * 16 + g * 4 + r;
        long col = col0 + wn * 64 + n * 16 + l15;
        float v = acc[m][n][r];
        if (isO1)
          O1[row * 768 + col] = __float2bfloat16(fmaxf(v, 0.0f));
        else
          O2[row * 768 + (col - 768)] = __float2bfloat16(v);
      }
}

// ---------- fused attention + gate: 64 c-rows, 4 waves, qlen-skip ----------
// Exact skip: cols >= qeff give exp->0 exactly (f32 underflow of -1e12 shift),
// so wave wc is "active" iff wc*64 < qeff; PV runs kk < ceil(qeff/32).
// qlen==0 -> qeff=256, no mask (softmax shift-invariance).
// LDS (bf16 el): As[2][2048] @0, Bs[2][8192] @4096, P[64*264] @20480,
// wred f32[256] @ el 37376, wsum @ +256 f32. Total 76800 B. 2 blocks/CU.
__global__ __launch_bounds__(256) void attn_kernel(
    const bf16* __restrict__ xcW, const bf16* __restrict__ xqW,
    const bf16* __restrict__ xqVT, const bf16* __restrict__ G1,
    const int* __restrict__ qlen_arr, float* __restrict__ out) {
  extern __shared__ __align__(16) bf16 smem[];
  bf16* P = smem + 20480;
  float* wred = (float*)(smem + 37376);   // [64][4]
  float* wsum = wred + 256;               // [64][4]

  // batch-interleaved mapping; dynamic HW backfill balances variable qlen
  const int n = blockIdx.x;       // 0..511
  const int b = n & 15;
  const int ct = n >> 4;          // 0..31

  const int tid = threadIdx.x;
  const int wc = tid >> 6;        // 0..3
  const int lane = tid & 63;
  const int l16 = lane & 15;
  const int kh = lane >> 4;

  const int qlen = qlen_arr[b];
  const int qeff = (qlen == 0) ? 256 : qlen;   // qlen==0: uniform -1e12 shift
  const bool active = (wc * 64) < qeff;
  const int kkmax = (qeff + 31) >> 5;          // PV k-tiles

  const long crow0 = (long)b * 2048 + (long)ct * 64;
  const int srow = lane >> 2;
  const int sc = ((lane & 3) ^ swz(srow)) * 8;
  const int xcr = (kh ^ swz(l16)) * 8;

  const bf16* ap = xcW + (crow0 + wc * 16 + srow) * 768 + sc;
  const bf16* bp = xqW + ((long)b * 256 + wc * 64 + srow) * 768 + sc;

  auto stage = [&](int bufi, int k0) {
    gll16(ap + k0, smem + bufi * 2048 + wc * 512);
    if (active) {
      bf16* bd = smem + 4096 + bufi * 8192 + wc * 2048;
#pragma unroll
      for (int q = 0; q < 4; ++q)
        gll16(bp + q * 16 * 768 + k0, bd + q * 512);
    }
  };

  f32x4 acc[4][4] = {};
  stage(0, 0);

  for (int t = 0; t < 24; ++t) {
    const int cur = t & 1;
    if (t + 1 < 24) {
      stage(cur ^ 1, (t + 1) * 32);
      if (active)
        asm volatile("s_waitcnt vmcnt(5)" ::: "memory");
      else
        asm volatile("s_waitcnt vmcnt(1)" ::: "memory");
      __builtin_amdgcn_s_barrier();
    } else {
      asm volatile("s_waitcnt vmcnt(0)\n\ts_barrier" ::: "memory");
    }
    if (active) {
      const bf16* Ac = smem + cur * 2048;
      const bf16* Bc = smem + 4096 + cur * 8192;
      bf16x8 af[4], bfr[4];
#pragma unroll
      for (int i = 0; i < 4; ++i)
        af[i] = ld_frag(Ac + (i * 16 + l16) * 32 + xcr);
#pragma unroll
      for (int j = 0; j < 4; ++j)
        bfr[j] = ld_frag(Bc + (wc * 64 + j * 16 + l16) * 32 + xcr);
      __builtin_amdgcn_s_setprio(1);
#pragma unroll
      for (int i = 0; i < 4; ++i)
#pragma unroll
        for (int j = 0; j < 4; ++j)
          acc[i][j] = mfma_bf16(af[i], bfr[j], acc[i][j]);
      __builtin_amdgcn_s_setprio(0);
    }
    __builtin_amdgcn_s_barrier();
  }

  const float scale = 0.036084391824351615f;  // 1/sqrt(768)

  if (active) {
#pragma unroll
    for (int i = 0; i < 4; ++i)
#pragma unroll
      for (int j = 0; j < 4; ++j) {
        int col = wc * 64 + j * 16 + l16;
        float m = (col >= qeff) ? -1.0e12f : 0.0f;
#pragma unroll
        for (int r = 0; r < 4; ++r)
          acc[i][j][r] = acc[i][j][r] * scale + m;
      }
#pragma unroll
    for (int i = 0; i < 4; ++i)
#pragma unroll
      for (int r = 0; r < 4; ++r) {
        float mx = fmaxf(fmaxf(acc[i][0][r], acc[i][1][r]),
                         fmaxf(acc[i][2][r], acc[i][3][r]));
        mx = fmaxf(mx, __shfl_xor(mx, 1));
        mx = fmaxf(mx, __shfl_xor(mx, 2));
        mx = fmaxf(mx, __shfl_xor(mx, 4));
        mx = fmaxf(mx, __shfl_xor(mx, 8));
        if (l16 == 0) wred[(i * 16 + kh * 4 + r) * 4 + wc] = mx;
      }
  } else if (l16 == 0) {
#pragma unroll
    for (int i = 0; i < 4; ++i)
#pragma unroll
      for (int r = 0; r < 4; ++r)
        wred[(i * 16 + kh * 4 + r) * 4 + wc] = -3.0e38f;
  }
  __syncthreads();

  if (active) {
#pragma unroll
    for (int i = 0; i < 4; ++i)
#pragma unroll
      for (int r = 0; r < 4; ++r) {
        int row = i * 16 + kh * 4 + r;
        float gm = fmaxf(fmaxf(wred[row * 4 + 0], wred[row * 4 + 1]),
                         fmaxf(wred[row * 4 + 2], wred[row * 4 + 3]));
        float s = 0.0f;
#pragma unroll
        for (int j = 0; j < 4; ++j) {
          float e = expf(acc[i][j][r] - gm);
          acc[i][j][r] = e;
          s += e;
        }
        s += __shfl_xor(s, 1);
        s += __shfl_xor(s, 2);
        s += __shfl_xor(s, 4);
        s += __shfl_xor(s, 8);
        if (l16 == 0) wsum[row * 4 + wc] = s;
      }
  } else if (l16 == 0) {
#pragma unroll
    for (int i = 0; i < 4; ++i)
#pragma unroll
      for (int r = 0; r < 4; ++r)
        wsum[(i * 16 + kh * 4 + r) * 4 + wc] = 0.0f;
  }
  __syncthreads();

  if (active) {
#pragma unroll
    for (int i = 0; i < 4; ++i)
#pragma unroll
      for (int r = 0; r < 4; ++r) {
        int row = i * 16 + kh * 4 + r;
        float inv = 1.0f / (wsum[row * 4 + 0] + wsum[row * 4 + 1] +
                            wsum[row * 4 + 2] + wsum[row * 4 + 3]);
#pragma unroll
        for (int j = 0; j < 4; ++j)
          P[row * 264 + wc * 64 + j * 16 + l16] = __float2bfloat16(acc[i][j][r] * inv);
      }
  }
  __syncthreads();

  // hoist P fragments (only the live k-range is read)
  bf16x8 pf[4][8];
#pragma unroll
  for (int kk = 0; kk < 8; ++kk) {
    if (kk >= kkmax) break;
#pragma unroll
    for (int i = 0; i < 4; ++i)
      pf[i][kk] = ld_frag(P + (i * 16 + l16) * 264 + kk * 32 + kh * 8);
  }

  for (int nb = 0; nb < 3; ++nb) {
    const int n0 = nb * 256 + wc * 64;
    const bf16* btp = xqVT + ((long)b * 768 + n0) * 256;
    f32x4 a2[4][4] = {};
#pragma unroll
    for (int kk = 0; kk < 8; ++kk) {
      if (kk >= kkmax) break;
      bf16x8 vf[4];
#pragma unroll
      for (int j = 0; j < 4; ++j)
        vf[j] = ld_frag(btp + (j * 16 + l16) * 256 + kk * 32 + kh * 8);
#pragma unroll
      for (int i = 0; i < 4; ++i)
#pragma unroll
        for (int j = 0; j < 4; ++j)
          a2[i][j] = mfma_bf16(pf[i][kk], vf[j], a2[i][j]);
    }
#pragma unroll
    for (int i = 0; i < 4; ++i)
#pragma unroll
      for (int j = 0; j < 4; ++j)
#pragma unroll
        for (int r = 0; r < 4; ++r) {
          long row = crow0 + i * 16 + kh * 4 + r;
          int col = n0 + j * 16 + l16;
          float v = a2[i][j][r] + __bfloat162float(G1[row * 768 + col]);
          out[row * 768 + col] = 1.0f / (1.0f + __expf(-v));
        }
  }
}

extern "C" void kernel_launch(void* const* d_in, const int* in_sizes, int n_in,
                              void* d_out, int out_size, void* d_ws, size_t ws_size,
                              hipStream_t stream) {
  const float* x_cont = (const float*)d_in[0];  // [16,2048,768]
  const float* x_ques = (const float*)d_in[1];  // [16,256,768]
  const int* ques_len = (const int*)d_in[2];    // [16]
  const float* WC = (const float*)d_in[3];      // [768,768]
  const float* WQ = (const float*)d_in[4];      // [768,768]
  const float* V = (const float*)d_in[5];       // [1536,768]
  float* out = (float*)d_out;                   // [32768,768] f32

  // ws layout (bf16 elements), ~181 MB total (same as round 4, which passed)
  bf16* Wct = (bf16*)d_ws;                       // [1536][768] = [WC^T ; Vtop^T]
  bf16* Wqt = Wct + (long)1536 * 768;            // [1536][768] = [WQ^T ; Vbot^T]
  bf16* xcB = Wqt + (long)1536 * 768;            // [32768][768]
  bf16* xqB = xcB + (long)32768 * 768;           // [4096][768]
  bf16* xcW = xqB + (long)4096 * 768;            // [32768][768]
  bf16* xqW = xcW + (long)32768 * 768;           // [4096][768]
  bf16* xqV = xqW + (long)4096 * 768;            // [4096][768]
  bf16* xqVT = xqV + (long)4096 * 768;           // [16][768][256]
  bf16* G1 = xqVT + (long)16 * 768 * 256;        // [32768][768]

  (void)hipFuncSetAttribute(reinterpret_cast<const void*>(&gemm4b),
                            hipFuncAttributeMaxDynamicSharedMemorySize, 131072);
  (void)hipFuncSetAttribute(reinterpret_cast<const void*>(&attn_kernel),
                            hipFuncAttributeMaxDynamicSharedMemorySize, 76800);

  // weight prep: Wct = [WC^T ; Vtop^T], Wqt = [WQ^T ; Vbot^T]
  transpose4<<<dim3(24, 24, 4), dim3(32, 8), 0, stream>>>(
      WC, WQ, V, V + (long)768 * 768,
      Wct, Wqt, Wct + (long)768 * 768, Wqt + (long)768 * 768);

  // input converts
  convert_flat<<<24576, 256, 0, stream>>>(x_cont, xcB, (long)32768 * 768 / 4);
  convert_flat<<<3072, 256, 0, stream>>>(x_ques, xqB, (long)4096 * 768 / 4);

  // xq fused projection: [xqW | xqV] = relu/id(xq @ [WQ | Vbot])
  gemm_bt_split<<<dim3(32, 12), 256, 0, stream>>>(xqB, 768, Wqt, 768, xqW, xqV, 768);
  transpose_bf16<<<dim3(24, 8, 16), dim3(32, 8), 0, stream>>>(
      xqV, xqVT, 256, 768, (long)256 * 768, (long)768 * 256);

  // xc fused projection: xcW (relu bf16) + G1 (bf16)
  gemm4b<<<768, 512, 131072, stream>>>(xcB, 768, Wct, 768, xcW, G1, 768);

  // attention + gate epilogue (qlen-skip)
  attn_kernel<<<512, 256, 76800, stream>>>(xcW, xqW, xqVT, G1, ques_len, out);
}

// Round 7
// 248.075 us; speedup vs baseline: 1.2305x; 1.0679x over previous
//
#include <hip/hip_runtime.h>
#include <hip/hip_bf16.h>
#include <cstdint>

// GateAttention, restructured:
//   xcW|G1 = xc @ [WC | V_top]   (relu on xcW half; G1 bf16 -> ws)
//   xqW|xqV = xq @ [WQ | V_bot]  (relu on xqW half)
//   attn: S = xcW.xqW^T, softmax+mask, O = P @ xqV, out = sigmoid(G1 + O)
// Round 7: attn rebuilt on the gemm4b skeleton: 128x256 blocks, 8 waves,
// 4-buf depth-3 QK pipeline (vmcnt(9) ledger), grid 256 = 1 block/CU,
// P overlays QK staging LDS. No qlen skip (round-6 showed it buys nothing).
// B=16, LC=2048, LQ=256, D=768, F=768.

using bf16 = __hip_bfloat16;
typedef __attribute__((ext_vector_type(8))) __bf16 bf16x8;
typedef __attribute__((ext_vector_type(4))) float f32x4;

typedef __attribute__((address_space(1))) const uint32_t GU32;
typedef __attribute__((address_space(3))) uint32_t LU32;

__device__ __forceinline__ void gll16(const bf16* g, bf16* l) {
  __builtin_amdgcn_global_load_lds((GU32*)g, (LU32*)l, 16, 0, 0);
}
__device__ __forceinline__ f32x4 mfma_bf16(bf16x8 a, bf16x8 b, f32x4 c) {
  return __builtin_amdgcn_mfma_f32_16x16x32_bf16(a, b, c, 0, 0, 0);
}
__device__ __forceinline__ bf16x8 ld_frag(const bf16* p) {
  return *reinterpret_cast<const bf16x8*>(p);
}
// LDS chunk swizzle (4 chunks of 16B per 64B row)
__device__ __forceinline__ int swz(int r) { return (r & 3) ^ ((r >> 2) & 1); }

__device__ __forceinline__ unsigned short f2bf_bits(float x) {
  bf16 b = __float2bfloat16(x);
  union { bf16 b; unsigned short s; } u;
  u.b = b;
  return u.s;
}

// ---------- 4x fused transpose f32 [768][768] -> bf16 [768][768]^T ----------
__global__ void transpose4(const float* __restrict__ s0, const float* __restrict__ s1,
                           const float* __restrict__ s2, const float* __restrict__ s3,
                           bf16* __restrict__ d0, bf16* __restrict__ d1,
                           bf16* __restrict__ d2, bf16* __restrict__ d3) {
  __shared__ float tile[32][33];
  const int z = blockIdx.z;
  const float* in = (z == 0) ? s0 : (z == 1) ? s1 : (z == 2) ? s2 : s3;
  bf16* out = (z == 0) ? d0 : (z == 1) ? d1 : (z == 2) ? d2 : d3;
  int c0 = blockIdx.x * 32, r0 = blockIdx.y * 32;
  int tx = threadIdx.x, ty = threadIdx.y;
#pragma unroll
  for (int i = ty; i < 32; i += 8)
    tile[i][tx] = in[(long)(r0 + i) * 768 + (c0 + tx)];
  __syncthreads();
#pragma unroll
  for (int i = ty; i < 32; i += 8)
    out[(long)(c0 + i) * 768 + (r0 + tx)] = __float2bfloat16(tile[tx][i]);
}

// ---------- transpose bf16 [R][C] -> bf16 [C][R], batched ----------
__global__ void transpose_bf16(const bf16* __restrict__ in, bf16* __restrict__ out,
                               int R, int C, long ibs, long obs) {
  __shared__ bf16 tile[32][33];
  const bf16* inb = in + (long)blockIdx.z * ibs;
  bf16* outb = out + (long)blockIdx.z * obs;
  int c0 = blockIdx.x * 32, r0 = blockIdx.y * 32;
  int tx = threadIdx.x, ty = threadIdx.y;
#pragma unroll
  for (int i = ty; i < 32; i += 8)
    tile[i][tx] = inb[(long)(r0 + i) * C + (c0 + tx)];
  __syncthreads();
#pragma unroll
  for (int i = ty; i < 32; i += 8)
    outb[(long)(c0 + i) * R + (r0 + tx)] = tile[tx][i];
}

// ---------- flat f32 -> bf16 convert ----------
__global__ void convert_flat(const float* __restrict__ in, bf16* __restrict__ out, long n4) {
  long i = (long)blockIdx.x * blockDim.x + threadIdx.x;
  if (i >= n4) return;
  float4 v = reinterpret_cast<const float4*>(in)[i];
  ushort4 o;
  o.x = f2bf_bits(v.x);
  o.y = f2bf_bits(v.y);
  o.z = f2bf_bits(v.z);
  o.w = f2bf_bits(v.w);
  reinterpret_cast<ushort4*>(out)[i] = o;
}

// ---------- 128x128 GEMM with split epilogue (small xq projection) ----------
__global__ __launch_bounds__(256) void gemm_bt_split(
    const bf16* __restrict__ A, long lda,
    const bf16* __restrict__ Bt, long ldb,
    bf16* __restrict__ O1, bf16* __restrict__ O2, int K) {
  __shared__ __align__(16) bf16 As[128 * 32];
  __shared__ __align__(16) bf16 Bs[128 * 32];
  const int tid = threadIdx.x;
  const int wave = tid >> 6;
  const int lane = tid & 63;
  const int l16 = lane & 15;
  const int kh = lane >> 4;
  const int wm = (wave >> 1) * 64;
  const int wn = (wave & 1) * 64;
  const long row0 = (long)blockIdx.x * 128;
  const long col0 = (long)blockIdx.y * 128;
  const int srow = tid >> 2;
  const int scol = ((tid & 3) ^ swz(srow)) * 8;

  const bf16* ap0 = A + (row0 + srow) * lda + scol;
  const bf16* ap1 = ap0 + 64 * lda;
  const bf16* bp0 = Bt + (col0 + srow) * ldb + scol;
  const bf16* bp1 = bp0 + 64 * ldb;
  bf16* as0 = As + wave * 512;
  bf16* as1 = as0 + 2048;
  bf16* bs0 = Bs + wave * 512;
  bf16* bs1 = bs0 + 2048;

  const int xc = (kh ^ swz(l16)) * 8;
  f32x4 acc[4][4] = {};

  for (int k0 = 0; k0 < K; k0 += 32) {
    gll16(ap0 + k0, as0);
    gll16(ap1 + k0, as1);
    gll16(bp0 + k0, bs0);
    gll16(bp1 + k0, bs1);
    __syncthreads();
    bf16x8 af[4], bfr[4];
#pragma unroll
    for (int i = 0; i < 4; ++i)
      af[i] = ld_frag(As + (wm + i * 16 + l16) * 32 + xc);
#pragma unroll
    for (int j = 0; j < 4; ++j)
      bfr[j] = ld_frag(Bs + (wn + j * 16 + l16) * 32 + xc);
#pragma unroll
    for (int i = 0; i < 4; ++i)
#pragma unroll
      for (int j = 0; j < 4; ++j)
        acc[i][j] = mfma_bf16(af[i], bfr[j], acc[i][j]);
    __syncthreads();
  }

  const bool isO1 = col0 < 768;
#pragma unroll
  for (int i = 0; i < 4; ++i)
#pragma unroll
    for (int j = 0; j < 4; ++j)
#pragma unroll
      for (int r = 0; r < 4; ++r) {
        long row = row0 + wm + i * 16 + kh * 4 + r;
        long col = col0 + wn + j * 16 + l16;
        float v = acc[i][j][r];
        if (isO1)
          O1[row * 768 + col] = __float2bfloat16(fmaxf(v, 0.0f));
        else
          O2[row * 768 + (col - 768)] = __float2bfloat16(v);
      }
}

// ---------- 256x256 GEMM, BK=32, 4-buffer LDS, 3-tile prefetch depth -------
// cols [0,768): relu -> O1 bf16 (xcW) ; cols [768,1536): plain -> O2 bf16 (G1).
__global__ __launch_bounds__(512, 2) void gemm4b(
    const bf16* __restrict__ A, long lda,
    const bf16* __restrict__ Bt, long ldb,
    bf16* __restrict__ O1, bf16* __restrict__ O2, int K) {
  extern __shared__ __align__(16) bf16 smem[];  // 4 bufs x (A 8192 + B 8192) bf16
  const int tid = threadIdx.x;
  const int wid = tid >> 6;
  const int lane = tid & 63;
  const int l15 = lane & 15;
  const int g = lane >> 4;
  const int wm = wid >> 2;
  const int wn = wid & 3;

  const int lin = blockIdx.x;          // 0..767
  const int per = (int)gridDim.x >> 3; // 96
  const int wgid = (lin & 7) * per + (lin >> 3);
  const long row0 = (long)(wgid / 6) * 256;
  const long col0 = (long)(wgid % 6) * 256;

  const int srow = lane >> 2;
  const int sc = ((lane & 3) ^ swz(srow)) * 8;
  const int w16 = wid * 16;
  const bf16* Ab = A + (row0 + srow) * lda + sc;
  const bf16* Bb = Bt + (col0 + srow) * ldb + sc;

  f32x4 acc[8][4] = {};

  auto stageA = [&](int buf, int kk) {
    bf16* d = smem + buf * 16384 + w16 * 32;
    gll16(Ab + (long)w16 * lda + kk, d);
    gll16(Ab + (long)(128 + w16) * lda + kk, d + 128 * 32);
  };
  auto stageB = [&](int buf, int kk) {
    bf16* d = smem + buf * 16384 + 8192 + w16 * 32;
    gll16(Bb + (long)w16 * ldb + kk, d);
    gll16(Bb + (long)(128 + w16) * ldb + kk, d + 128 * 32);
  };
  const int xc = (g ^ swz(l15)) * 8;
  auto ldA = [&](int buf, int m) {
    int row = wm * 128 + m * 16 + l15;
    return ld_frag(smem + buf * 16384 + row * 32 + xc);
  };
  auto ldB = [&](int buf, int n) {
    int row = wn * 64 + n * 16 + l15;
    return ld_frag(smem + buf * 16384 + 8192 + row * 32 + xc);
  };

  stageA(0, 0);
  stageB(0, 0);
  stageA(1, 32);
  stageB(1, 32);
  stageA(2, 64);
  stageB(2, 64);
  asm volatile("s_waitcnt vmcnt(8)\n\ts_barrier" ::: "memory");

  const int NT = K >> 5;  // 24
  bf16x8 av[4], bv[4];

  for (int t = 0; t < NT; ++t) {
    const int cur = t & 3;
    const int pfb = (t + 3) & 3;
    const bool pf = (t + 3) < NT;
    const int kk = (t + 3) << 5;

#pragma unroll
    for (int n = 0; n < 4; ++n) bv[n] = ldB(cur, n);
#pragma unroll
    for (int m = 0; m < 4; ++m) av[m] = ldA(cur, m);
    if (pf) stageA(pfb, kk);
    __builtin_amdgcn_s_barrier();
    __builtin_amdgcn_s_setprio(1);
#pragma unroll
    for (int m = 0; m < 4; ++m)
#pragma unroll
      for (int n = 0; n < 4; ++n) acc[m][n] = mfma_bf16(av[m], bv[n], acc[m][n]);
    __builtin_amdgcn_s_setprio(0);
    __builtin_amdgcn_s_barrier();

#pragma unroll
    for (int m = 0; m < 4; ++m) av[m] = ldA(cur, 4 + m);
    if (pf) stageB(pfb, kk);
    __builtin_amdgcn_s_barrier();
    __builtin_amdgcn_s_setprio(1);
#pragma unroll
    for (int m = 0; m < 4; ++m)
#pragma unroll
      for (int n = 0; n < 4; ++n)
        acc[4 + m][n] = mfma_bf16(av[m], bv[n], acc[4 + m][n]);
    __builtin_amdgcn_s_setprio(0);

    if (t <= NT - 4)
      asm volatile("s_waitcnt vmcnt(8)\n\ts_barrier" ::: "memory");
    else if (t == NT - 3)
      asm volatile("s_waitcnt vmcnt(4)\n\ts_barrier" ::: "memory");
    else if (t == NT - 2)
      asm volatile("s_waitcnt vmcnt(0)\n\ts_barrier" ::: "memory");
  }

  const bool isO1 = col0 < 768;
#pragma unroll
  for (int m = 0; m < 8; ++m)
#pragma unroll
    for (int n = 0; n < 4; ++n)
#pragma unroll
      for (int r = 0; r < 4; ++r) {
        long row = row0 + wm * 128 + m * 16 + g * 4 + r;
        long col = col0 + wn * 64 + n * 16 + l15;
        float v = acc[m][n][r];
        if (isO1)
          O1[row * 768 + col] = __float2bfloat16(fmaxf(v, 0.0f));
        else
          O2[row * 768 + (col - 768)] = __float2bfloat16(v);
      }
}

// ---------- fused attention + gate: 128 c-rows x 256 q-cols, 8 waves -------
// QK on the gemm4b skeleton: 4 bufs, depth-3, vmcnt(9) ledger, 2 barriers/it.
// LDS (bf16 el): bufs[4] @ buf*12288 (A[128][32] + B[256][32]) = 96KB;
// P[128][264] overlays bufs 0-2 (els 0..33791); wred f32[512] @ el 49152,
// wsum @ +512 f32. Total 102400 B -> 1 block/CU. Grid 256 = 1 round.
__global__ __launch_bounds__(512) void attn3(
    const bf16* __restrict__ xcW, const bf16* __restrict__ xqW,
    const bf16* __restrict__ xqVT, const bf16* __restrict__ G1,
    const int* __restrict__ qlen_arr, float* __restrict__ out) {
  extern __shared__ __align__(16) bf16 smem[];
  bf16* P = smem;                          // overlays bufs 0-2 post-QK
  float* wred = (float*)(smem + 49152);    // [128][4]
  float* wsum = wred + 512;                // [128][4]

  // XCD-chunked: XCD x serves batches 2x,2x+1 (16 row-tiles each)
  const int lin = blockIdx.x;     // 0..255
  const int xcd = lin & 7;
  const int jj = lin >> 3;        // 0..31
  const int b = xcd * 2 + (jj >> 4);
  const int ct = jj & 15;

  const int tid = threadIdx.x;
  const int wid = tid >> 6;
  const int lane = tid & 63;
  const int l16 = lane & 15;
  const int kh = lane >> 4;
  const int wm = wid >> 2;   // 0..1
  const int wn = wid & 3;    // 0..3

  const long crow0 = (long)b * 2048 + (long)ct * 128;
  const int srow = lane >> 2;
  const int sc = ((lane & 3) ^ swz(srow)) * 8;
  const int xcr = (kh ^ swz(l16)) * 8;

  const bf16* ap = xcW + (crow0 + wid * 16 + srow) * 768 + sc;
  const bf16* bp = xqW + ((long)b * 256 + wid * 32 + srow) * 768 + sc;
  const bf16* bp2 = bp + 16 * 768;

  auto stage = [&](int buf, int k0) {
    gll16(ap + k0, smem + buf * 12288 + wid * 512);
    bf16* bd = smem + buf * 12288 + 4096 + wid * 1024;
    gll16(bp + k0, bd);
    gll16(bp2 + k0, bd + 512);
  };

  f32x4 acc[4][4] = {};
  stage(0, 0);
  stage(1, 32);
  stage(2, 64);

  for (int t = 0; t < 24; ++t) {
    const int cur = t & 3;
    if (t + 3 < 24) stage((t + 3) & 3, (t + 3) * 32);
    if (t <= 20)
      asm volatile("s_waitcnt vmcnt(9)\n\ts_barrier" ::: "memory");
    else if (t == 21)
      asm volatile("s_waitcnt vmcnt(6)\n\ts_barrier" ::: "memory");
    else if (t == 22)
      asm volatile("s_waitcnt vmcnt(3)\n\ts_barrier" ::: "memory");
    else
      asm volatile("s_waitcnt vmcnt(0)\n\ts_barrier" ::: "memory");

    const bf16* Ac = smem + cur * 12288;
    const bf16* Bc = Ac + 4096;
    bf16x8 af[4], bfr[4];
#pragma unroll
    for (int i = 0; i < 4; ++i)
      af[i] = ld_frag(Ac + (wm * 64 + i * 16 + l16) * 32 + xcr);
#pragma unroll
    for (int j = 0; j < 4; ++j)
      bfr[j] = ld_frag(Bc + (wn * 64 + j * 16 + l16) * 32 + xcr);
    __builtin_amdgcn_s_setprio(1);
#pragma unroll
    for (int i = 0; i < 4; ++i)
#pragma unroll
      for (int j = 0; j < 4; ++j)
        acc[i][j] = mfma_bf16(af[i], bfr[j], acc[i][j]);
    __builtin_amdgcn_s_setprio(0);
    __builtin_amdgcn_s_barrier();  // protect buf cur from next-iter stage
  }

  const float scale = 0.036084391824351615f;  // 1/sqrt(768)
  const int qlen = qlen_arr[b];

#pragma unroll
  for (int i = 0; i < 4; ++i)
#pragma unroll
    for (int j = 0; j < 4; ++j) {
      int col = wn * 64 + j * 16 + l16;
      float m = (col >= qlen) ? -1.0e12f : 0.0f;
#pragma unroll
      for (int r = 0; r < 4; ++r)
        acc[i][j][r] = acc[i][j][r] * scale + m;
    }

#pragma unroll
  for (int i = 0; i < 4; ++i)
#pragma unroll
    for (int r = 0; r < 4; ++r) {
      float mx = fmaxf(fmaxf(acc[i][0][r], acc[i][1][r]),
                       fmaxf(acc[i][2][r], acc[i][3][r]));
      mx = fmaxf(mx, __shfl_xor(mx, 1));
      mx = fmaxf(mx, __shfl_xor(mx, 2));
      mx = fmaxf(mx, __shfl_xor(mx, 4));
      mx = fmaxf(mx, __shfl_xor(mx, 8));
      if (l16 == 0) wred[(wm * 64 + i * 16 + kh * 4 + r) * 4 + wn] = mx;
    }
  __syncthreads();

#pragma unroll
  for (int i = 0; i < 4; ++i)
#pragma unroll
    for (int r = 0; r < 4; ++r) {
      int row = wm * 64 + i * 16 + kh * 4 + r;
      float gm = fmaxf(fmaxf(wred[row * 4 + 0], wred[row * 4 + 1]),
                       fmaxf(wred[row * 4 + 2], wred[row * 4 + 3]));
      float s = 0.0f;
#pragma unroll
      for (int j = 0; j < 4; ++j) {
        float e = expf(acc[i][j][r] - gm);
        acc[i][j][r] = e;
        s += e;
      }
      s += __shfl_xor(s, 1);
      s += __shfl_xor(s, 2);
      s += __shfl_xor(s, 4);
      s += __shfl_xor(s, 8);
      if (l16 == 0) wsum[row * 4 + wn] = s;
    }
  __syncthreads();  // also separates last QK ds_read from P overlay writes

#pragma unroll
  for (int i = 0; i < 4; ++i)
#pragma unroll
    for (int r = 0; r < 4; ++r) {
      int row = wm * 64 + i * 16 + kh * 4 + r;
      float inv = 1.0f / (wsum[row * 4 + 0] + wsum[row * 4 + 1] +
                          wsum[row * 4 + 2] + wsum[row * 4 + 3]);
#pragma unroll
      for (int j = 0; j < 4; ++j)
        P[row * 264 + wn * 64 + j * 16 + l16] = __float2bfloat16(acc[i][j][r] * inv);
    }
  __syncthreads();

  // hoist P fragments (reused across all 3 nb sweeps)
  bf16x8 pf[4][8];
#pragma unroll
  for (int i = 0; i < 4; ++i)
#pragma unroll
    for (int kk = 0; kk < 8; ++kk)
      pf[i][kk] = ld_frag(P + (wm * 64 + i * 16 + l16) * 264 + kk * 32 + kh * 8);

  for (int nb = 0; nb < 3; ++nb) {
    const int n0 = nb * 256 + wn * 64;
    const bf16* btp = xqVT + ((long)b * 768 + n0) * 256;
    f32x4 a2[4][4] = {};
#pragma unroll
    for (int kk = 0; kk < 8; ++kk) {
      bf16x8 vf[4];
#pragma unroll
      for (int j = 0; j < 4; ++j)
        vf[j] = ld_frag(btp + (j * 16 + l16) * 256 + kk * 32 + kh * 8);
#pragma unroll
      for (int i = 0; i < 4; ++i)
#pragma unroll
        for (int j = 0; j < 4; ++j)
          a2[i][j] = mfma_bf16(pf[i][kk], vf[j], a2[i][j]);
    }
#pragma unroll
    for (int i = 0; i < 4; ++i)
#pragma unroll
      for (int j = 0; j < 4; ++j)
#pragma unroll
        for (int r = 0; r < 4; ++r) {
          long row = crow0 + wm * 64 + i * 16 + kh * 4 + r;
          int col = n0 + j * 16 + l16;
          float v = a2[i][j][r] + __bfloat162float(G1[row * 768 + col]);
          out[row * 768 + col] = 1.0f / (1.0f + __expf(-v));
        }
  }
}

extern "C" void kernel_launch(void* const* d_in, const int* in_sizes, int n_in,
                              void* d_out, int out_size, void* d_ws, size_t ws_size,
                              hipStream_t stream) {
  const float* x_cont = (const float*)d_in[0];  // [16,2048,768]
  const float* x_ques = (const float*)d_in[1];  // [16,256,768]
  const int* ques_len = (const int*)d_in[2];    // [16]
  const float* WC = (const float*)d_in[3];      // [768,768]
  const float* WQ = (const float*)d_in[4];      // [768,768]
  const float* V = (const float*)d_in[5];       // [1536,768]
  float* out = (float*)d_out;                   // [32768,768] f32

  // ws layout (bf16 elements)
  bf16* Wct = (bf16*)d_ws;                       // [1536][768] = [WC^T ; Vtop^T]
  bf16* Wqt = Wct + (long)1536 * 768;            // [1536][768] = [WQ^T ; Vbot^T]
  bf16* xcB = Wqt + (long)1536 * 768;            // [32768][768]
  bf16* xqB = xcB + (long)32768 * 768;           // [4096][768]
  bf16* xcW = xqB + (long)4096 * 768;            // [32768][768]
  bf16* xqW = xcW + (long)32768 * 768;           // [4096][768]
  bf16* xqV = xqW + (long)4096 * 768;            // [4096][768]
  bf16* xqVT = xqV + (long)4096 * 768;           // [16][768][256]
  bf16* G1 = xqVT + (long)16 * 768 * 256;        // [32768][768]

  (void)hipFuncSetAttribute(reinterpret_cast<const void*>(&gemm4b),
                            hipFuncAttributeMaxDynamicSharedMemorySize, 131072);
  (void)hipFuncSetAttribute(reinterpret_cast<const void*>(&attn3),
                            hipFuncAttributeMaxDynamicSharedMemorySize, 102400);

  // weight prep: Wct = [WC^T ; Vtop^T], Wqt = [WQ^T ; Vbot^T]
  transpose4<<<dim3(24, 24, 4), dim3(32, 8), 0, stream>>>(
      WC, WQ, V, V + (long)768 * 768,
      Wct, Wqt, Wct + (long)768 * 768, Wqt + (long)768 * 768);

  // input converts
  convert_flat<<<24576, 256, 0, stream>>>(x_cont, xcB, (long)32768 * 768 / 4);
  convert_flat<<<3072, 256, 0, stream>>>(x_ques, xqB, (long)4096 * 768 / 4);

  // xq fused projection: [xqW | xqV] = relu/id(xq @ [WQ | Vbot])
  gemm_bt_split<<<dim3(32, 12), 256, 0, stream>>>(xqB, 768, Wqt, 768, xqW, xqV, 768);
  transpose_bf16<<<dim3(24, 8, 16), dim3(32, 8), 0, stream>>>(
      xqV, xqVT, 256, 768, (long)256 * 768, (long)768 * 256);

  // xc fused projection: xcW (relu bf16) + G1 (bf16)
  gemm4b<<<768, 512, 131072, stream>>>(xcB, 768, Wct, 768, xcW, G1, 768);

  // attention + gate epilogue
  attn3<<<256, 512, 102400, stream>>>(xcW, xqW, xqVT, G1, ques_len, out);
}